// Round 7
// baseline (275.692 us; speedup 1.0000x reference)
//
#include <hip/hip_runtime.h>

#define S_LEN 2048
#define DMODEL 1024
#define NHEADS 16
#define DKH 64

typedef __attribute__((ext_vector_type(8))) short bf16x8;
typedef __attribute__((ext_vector_type(4))) float f32x4;

#if __has_builtin(__builtin_amdgcn_exp2f)
#define EXP2F(x) __builtin_amdgcn_exp2f(x)
#define QSCALE (0.125f * 1.44269504f)
#else
#define EXP2F(x) __expf(x)
#define QSCALE 0.125f
#endif

static __device__ __forceinline__ short f2bf(float f) {
    unsigned b = __float_as_uint(f);
    b = (b + 0x7FFFu + ((b >> 16) & 1u)) >> 16;   // RNE
    return (short)b;
}

// pack truncated-bf16 of (lo,hi) into one u32
static __device__ __forceinline__ unsigned pktrunc(float lo, float hi) {
#if __has_builtin(__builtin_amdgcn_perm)
    return __builtin_amdgcn_perm(__float_as_uint(hi), __float_as_uint(lo), 0x07060302u);
#else
    return (__float_as_uint(lo) >> 16) | (__float_as_uint(hi) & 0xFFFF0000u);
#endif
}

static __device__ __forceinline__ f32x4 mfma16(bf16x8 a, bf16x8 b, f32x4 c) {
    return __builtin_amdgcn_mfma_f32_16x16x32_bf16(a, b, c, 0, 0, 0);
}

static __device__ __forceinline__ void glds16(const short* g, short* l) {
    __builtin_amdgcn_global_load_lds(
        (const __attribute__((address_space(1))) void*)g,
        (__attribute__((address_space(3))) void*)l, 16, 0, 0);
}

// ---------------------------------------------------------------------------
// prep: fused fp32->bf16 convert (blocks 0..8191) + mask bit-pack (2048 blocks)
// ---------------------------------------------------------------------------
struct CvtArgs { const float* src[7]; short* dst[7]; };

__global__ __launch_bounds__(256) void prep(CvtArgs a, const int* __restrict__ mask,
                                            unsigned long long* __restrict__ mw) {
    if (blockIdx.x < 8192) {
        const size_t i8 = ((size_t)blockIdx.x * 256 + threadIdx.x) * 8;
        int seg; size_t off;
        if (i8 < ((size_t)12 << 20)) { seg = (int)(i8 >> 22); off = i8 & ((1u << 22) - 1); }
        else { size_t r = i8 - ((size_t)12 << 20); seg = 3 + (int)(r >> 20); off = r & ((1u << 20) - 1); }
        const float* s = a.src[seg] + off;
        float4 x0 = *(const float4*)s, x1 = *(const float4*)(s + 4);
        short o[8];
        o[0] = f2bf(x0.x); o[1] = f2bf(x0.y); o[2] = f2bf(x0.z); o[3] = f2bf(x0.w);
        o[4] = f2bf(x1.x); o[5] = f2bf(x1.y); o[6] = f2bf(x1.z); o[7] = f2bf(x1.w);
        *(uint4*)(a.dst[seg] + off) = *(uint4*)o;
    } else {
        const int wv = ((blockIdx.x - 8192) << 2) + (threadIdx.x >> 6);
        const int lane = threadIdx.x & 63;
        const size_t base = (size_t)wv << 4;
        #pragma unroll 4
        for (int it = 0; it < 16; ++it) {
            const size_t w = base + it;
            const int m = mask[(w << 6) + lane];
            unsigned long long bal = __ballot(m != 0);
            if (lane == 0) mw[w] = bal;
        }
    }
}

// ---------------------------------------------------------------------------
// C = X @ W^T + bias, bf16, BK=32, glds16 staging, single-barrier
// double-buffered K-loop. TM = m-tile (128 or 64), n-tile fixed 128.
// MODE 0 (TM=128): z<2 -> bf16 headed [BH][S][DKH] (scaled); z==2 ->
// transposed headed kt[bh][d][s'] with kappa-permuted s (PV k32 layout).
// MODE 1: fp32 flat [M][N].
// ---------------------------------------------------------------------------
struct GemmArgs { const short* X[3]; const short* W[3]; const float* B[3];
                  void* C[3]; float scale[3]; };

template <int MODE, int TM>
__global__ __launch_bounds__(256) void gemm_bt(GemmArgs a) {
    __shared__ short Ah[2][TM * 32];
    __shared__ short Bh[2][128 * 32];
    const int z = blockIdx.z;
    const short* X = a.X[z];
    const short* W = a.W[z];
    const float* bias = a.B[z];
    const float scl = a.scale[z];

    const int t = threadIdx.x, wid = t >> 6, lane = t & 63;
    const int l15 = lane & 15, lq = lane >> 4;
    int m0, n0;
    if (MODE == 0 && z == 2) { m0 = blockIdx.y << 7; n0 = blockIdx.x << 7; }
    else { m0 = (TM == 128) ? (blockIdx.x << 7) : (blockIdx.x << 6); n0 = blockIdx.y << 7; }
    constexpr int IT = (TM == 128) ? 4 : 2;
    const int wm = (TM == 128) ? ((wid >> 1) << 6) : ((wid >> 1) << 5);
    const int wn = (wid & 1) << 6;

    const int kb = (lane & 3) ^ ((lane >> 3) & 3);
    const short *ag0, *ag1 = nullptr;
    int aoff0, aoff1 = 0;
    if (TM == 128) {
        const int r0 = (wid << 5) + (lane >> 2);
        ag0 = X + (size_t)(m0 + r0) * 1024 + (kb << 3);
        ag1 = ag0 + 16 * 1024;
        aoff0 = (wid << 5) * 32;
        aoff1 = aoff0 + 16 * 32;
    } else {
        const int r0 = (wid << 4) + (lane >> 2);
        ag0 = X + (size_t)(m0 + r0) * 1024 + (kb << 3);
        aoff0 = (wid << 4) * 32;
    }
    const int rb = (wid << 5) + (lane >> 2);
    const short* bg0 = W + (size_t)(n0 + rb) * 1024 + (kb << 3);
    const short* bg1 = bg0 + 16 * 1024;
    const int boff0 = (wid << 5) * 32, boff1 = boff0 + 16 * 32;

    const int fpos = (lq ^ ((l15 >> 1) & 3)) << 3;

    f32x4 acc[IT][4] = {};

    // prologue: stage k-block 0 into buffer 0
    glds16(ag0, Ah[0] + aoff0);
    if (TM == 128) glds16(ag1, Ah[0] + aoff1);
    glds16(bg0, Bh[0] + boff0);
    glds16(bg1, Bh[0] + boff1);

    for (int kc = 0; kc < 32; ++kc) {
        __syncthreads();                       // buf[kc&1] staged, buf[1-kc&1] free
        if (kc < 31) {
            const int nb = (kc + 1) & 1;
            const int ko = (kc + 1) << 5;
            glds16(ag0 + ko, Ah[nb] + aoff0);
            if (TM == 128) glds16(ag1 + ko, Ah[nb] + aoff1);
            glds16(bg0 + ko, Bh[nb] + boff0);
            glds16(bg1 + ko, Bh[nb] + boff1);
        }
        const short* Ac = Ah[kc & 1];
        const short* Bc = Bh[kc & 1];

        bf16x8 af[IT], bfr[4];
        #pragma unroll
        for (int i = 0; i < IT; ++i)
            af[i] = *(const bf16x8*)&Ac[(wm + i * 16 + l15) * 32 + fpos];
        #pragma unroll
        for (int j = 0; j < 4; ++j)
            bfr[j] = *(const bf16x8*)&Bc[(wn + j * 16 + l15) * 32 + fpos];
        #pragma unroll
        for (int i = 0; i < IT; ++i)
            #pragma unroll
            for (int j = 0; j < 4; ++j)
                acc[i][j] = mfma16(af[i], bfr[j], acc[i][j]);
    }

    if (MODE == 0 && z == 2) {
        // transposed headed write with kappa permutation of sequence index
        #pragma unroll
        for (int i = 0; i < 4; ++i) {
            #pragma unroll
            for (int r = 0; r < 4; ++r) {
                const int o = m0 + wm + i * 16 + (lq << 2) + r;
                const float bo_ = bias[o];
                const int h = o >> 6, d = o & 63;
                #pragma unroll
                for (int j = 0; j < 4; ++j) {
                    const int n = n0 + wn + j * 16 + l15;
                    const int bb = n >> 11;
                    const int j5 = n & 31;
                    const int kap = ((j5 >> 2) & 3) * 8 + ((j5 >> 4) & 1) * 4 + (j5 & 3);
                    const int sp = (n & 2047 & ~31) | kap;
                    ((short*)a.C[2])[(((size_t)((bb * 16 + h) << 6) + d) << 11) + sp] =
                        f2bf(acc[i][j][r] + bo_);
                }
            }
        }
        return;
    }

    #pragma unroll
    for (int j = 0; j < 4; ++j) {
        const int n = n0 + wn + j * 16 + l15;
        const float bn = bias[n];
        #pragma unroll
        for (int i = 0; i < IT; ++i) {
            const int mbase = m0 + wm + i * 16 + (lq << 2);
            #pragma unroll
            for (int r = 0; r < 4; ++r) {
                const float val = (acc[i][j][r] + bn) * scl;
                const int m = mbase + r;
                if (MODE == 0) {
                    const int b = m >> 11, s = m & 2047, h = n >> 6, d = n & 63;
                    ((short*)a.C[z])[((((size_t)(b * 16 + h)) << 11) + s) * 64 + d] = f2bf(val);
                } else {
                    ((float*)a.C[z])[((size_t)m << 10) + n] = val;
                }
            }
        }
    }
}

// ---------------------------------------------------------------------------
// attn5: transposed-S flash attention (reference K/V swap), all-k32 MFMA.
// S^T = V@Q^T (C: col=i=l15, row=j=lq*4+r); exp'd scores pair-concatenate in
// registers into k32 A-frags (kappa layout); kt pre-stores the matching
// permutation so K B-frags are contiguous b128. l via ones-MFMA (exact sum of
// the truncated P). Single-barrier double-buffered V/K staging via glds16.
// j-split z=2; partials merged by `combine`. Grid (16, 32, 2), 4 waves.
// ---------------------------------------------------------------------------
__global__ __launch_bounds__(256, 4) void attn5(
    const short* __restrict__ Qh, const short* __restrict__ Vh,
    const short* __restrict__ Kt, const unsigned long long* __restrict__ MW,
    short* __restrict__ Opart, float* __restrict__ lpart)
{
    __shared__ short Vs[2][64 * 64];   // [j][d], 16B-chunk xor-swizzled
    __shared__ short Ks[2][64 * 64];   // [d][kappa(j)], 16B-chunk xor-swizzled

    const int t = threadIdx.x, wid = t >> 6, lane = t & 63;
    const int l15 = lane & 15, lq = lane >> 4;
    const int bh = blockIdx.y, b = bh >> 4;
    const int z = blockIdx.z;
    const int ib = (blockIdx.x << 7) + (wid << 5);
    const int jbase = z << 10;

    // Q B-frags: B[n=i][k=d]
    bf16x8 qf[2][2];
    #pragma unroll
    for (int it = 0; it < 2; ++it) {
        const short* qp = Qh + ((size_t)bh * 2048 + ib + it * 16 + l15) * 64 + (lq << 3);
        qf[it][0] = *(const bf16x8*)qp;
        qf[it][1] = *(const bf16x8*)(qp + 32);
    }

    // staging: each wave stages 16 rows of V and 16 d-rows of Kt per chunk
    const int sr = lane >> 3, pc = lane & 7;
    const int lc = pc ^ sr;
    const int wr = wid << 4;
    const short* vsrc = Vh + (size_t)bh * 131072 + (size_t)(jbase + wr + sr) * 64 + (lc << 3);
    const short* ksrc = Kt + (size_t)bh * 131072 + (size_t)(wr + sr) * 2048 + jbase + (lc << 3);
    const int sdst = (wr << 6);

    const unsigned long long* mwp0 = MW + ((size_t)b * 2048 + ib + l15) * 32 + (z << 4);
    const unsigned long long* mwp1 = mwp0 + (size_t)16 * 32;

    const int x7 = l15 & 7;
    int off[2];
    #pragma unroll
    for (int p = 0; p < 2; ++p) off[p] = (((p << 2) + lq) ^ x7) << 3;

    f32x4 O[2][4] = {};
    f32x4 lsum[2] = {};
    bf16x8 ones8;
    #pragma unroll
    for (int e = 0; e < 8; ++e) ones8[e] = (short)0x3F80;

    // prologue: stage chunk 0 into buffer 0
    glds16(vsrc, Vs[0] + sdst);
    glds16(vsrc + 512, Vs[0] + sdst + 512);
    glds16(ksrc, Ks[0] + sdst);
    glds16(ksrc + 8 * 2048, Ks[0] + sdst + 512);

    for (int jc = 0; jc < 16; ++jc) {
        __syncthreads();                     // buf[jc&1] staged, buf[1-jc&1] free
        if (jc < 15) {
            const int nb = (jc + 1) & 1;
            const short* v2 = vsrc + (size_t)(jc + 1) * 4096;
            const short* k2 = ksrc + (jc + 1) * 64;
            glds16(v2, Vs[nb] + sdst);
            glds16(v2 + 512, Vs[nb] + sdst + 512);
            glds16(k2, Ks[nb] + sdst);
            glds16(k2 + 8 * 2048, Ks[nb] + sdst + 512);
        }
        const short* vbuf = Vs[jc & 1];
        const short* kbuf = Ks[jc & 1];

        uint2 mword[2];
        mword[0] = *(const uint2*)(mwp0 + jc);
        mword[1] = *(const uint2*)(mwp1 + jc);

        // V A-frags: A[m=j][k=d]
        bf16x8 vf[4][2];
        #pragma unroll
        for (int jt = 0; jt < 4; ++jt) {
            const short* vp = &vbuf[((jt << 4) + l15) << 6];
            vf[jt][0] = *(const bf16x8*)(vp + off[0]);
            vf[jt][1] = *(const bf16x8*)(vp + off[1]);
        }

        // S^T tiles -> exp -> pair-concatenated k32 A-frags; l via ones-MFMA
        bf16x8 pa8[2][2];
        #pragma unroll
        for (int it = 0; it < 2; ++it) {
            const unsigned wx = mword[it].x, wy = mword[it].y;
            uint2 uu[4];
            #pragma unroll
            for (int jt = 0; jt < 4; ++jt) {
                f32x4 sc = {};
                sc = mfma16(vf[jt][0], qf[it][0], sc);
                sc = mfma16(vf[jt][1], qf[it][1], sc);
                const unsigned w32 = (jt < 2) ? wx : wy;
                float p[4];
                #pragma unroll
                for (int r = 0; r < 4; ++r) {
                    const unsigned bit = (w32 >> (((jt & 1) << 4) + (lq << 2) + r)) & 1u;
                    const float e = EXP2F(sc[r]);
                    p[r] = bit ? e : 0.f;
                }
                uu[jt].x = pktrunc(p[0], p[1]);
                uu[jt].y = pktrunc(p[2], p[3]);
            }
            uint4 u0, u1;
            u0.x = uu[0].x; u0.y = uu[0].y; u0.z = uu[1].x; u0.w = uu[1].y;
            u1.x = uu[2].x; u1.y = uu[2].y; u1.z = uu[3].x; u1.w = uu[3].y;
            pa8[it][0] = __builtin_bit_cast(bf16x8, u0);
            pa8[it][1] = __builtin_bit_cast(bf16x8, u1);
            lsum[it] = mfma16(pa8[it][0], ones8, lsum[it]);
            lsum[it] = mfma16(pa8[it][1], ones8, lsum[it]);
        }

        // O += P @ K : B[n=d][k=kappa(j)] contiguous b128 from swizzled Ks
        #pragma unroll
        for (int dt = 0; dt < 4; ++dt) {
            const short* kp = &kbuf[((dt << 4) + l15) << 6];
            const bf16x8 kf0 = *(const bf16x8*)(kp + off[0]);
            const bf16x8 kf1 = *(const bf16x8*)(kp + off[1]);
            #pragma unroll
            for (int it = 0; it < 2; ++it) {
                O[it][dt] = mfma16(pa8[it][0], kf0, O[it][dt]);
                O[it][dt] = mfma16(pa8[it][1], kf1, O[it][dt]);
            }
        }
    }

    // epilogue: rows i = lq*4+r; cols d = dt*16+l15; l from col 0
    const size_t zb = (size_t)((z << 5) + bh) * 2048;
    #pragma unroll
    for (int it = 0; it < 2; ++it) {
        const int rb2 = ib + (it << 4) + (lq << 2);
        if (l15 == 0) {
            #pragma unroll
            for (int r = 0; r < 4; ++r)
                lpart[zb + rb2 + r] = lsum[it][r];
        }
        #pragma unroll
        for (int dt = 0; dt < 4; ++dt)
            #pragma unroll
            for (int r = 0; r < 4; ++r)
                Opart[(zb + rb2 + r) * 64 + (dt << 4) + l15] = f2bf(O[it][dt][r]);
    }
}

// ---------------------------------------------------------------------------
// combine: attr[b][s][h*64+d] = (O0+O1)/(l0+l1), bf16 out
// ---------------------------------------------------------------------------
__global__ __launch_bounds__(256) void combine(const short* __restrict__ Op,
                                               const float* __restrict__ lp,
                                               short* __restrict__ attr) {
    const int idx = blockIdx.x * 256 + threadIdx.x;      // 524288 total
    const int d8 = (idx & 7) << 3;
    const int srow = (idx >> 3) & 2047;
    const int bh = idx >> 14, b = bh >> 4, h = bh & 15;
    const size_t r0 = (size_t)bh * 2048 + srow;
    const size_t r1 = r0 + (size_t)32 * 2048;
    uint4 a = *(const uint4*)(Op + r0 * 64 + d8);
    uint4 c = *(const uint4*)(Op + r1 * 64 + d8);
    const float inv = 1.f / (lp[r0] + lp[r1]);
    const unsigned* au = (const unsigned*)&a;
    const unsigned* cu = (const unsigned*)&c;
    short o[8];
    #pragma unroll
    for (int i = 0; i < 4; ++i) {
        const float a0 = __uint_as_float(au[i] << 16);
        const float a1 = __uint_as_float(au[i] & 0xFFFF0000u);
        const float c0 = __uint_as_float(cu[i] << 16);
        const float c1 = __uint_as_float(cu[i] & 0xFFFF0000u);
        o[2 * i + 0] = f2bf((a0 + c0) * inv);
        o[2 * i + 1] = f2bf((a1 + c1) * inv);
    }
    *(uint4*)&attr[((size_t)b * 2048 + srow) * 1024 + (h << 6) + d8] = *(uint4*)o;
}

// ---------------------------------------------------------------------------
extern "C" void kernel_launch(void* const* d_in, const int* in_sizes, int n_in,
                              void* d_out, int out_size, void* d_ws, size_t ws_size,
                              hipStream_t stream) {
    const float* value = (const float*)d_in[0];
    const float* key   = (const float*)d_in[1];
    const float* query = (const float*)d_in[2];
    const int*   mask  = (const int*)d_in[3];
    const float* bv = (const float*)d_in[5];
    const float* bk = (const float*)d_in[7];
    const float* bq = (const float*)d_in[9];
    const float* bo = (const float*)d_in[11];
    float* out = (float*)d_out;

    const size_t M1 = (size_t)1 << 20, M4 = (size_t)1 << 22;
    short* ws = (short*)d_ws;
    short* Xq = ws;                       // reused as attr after proj
    short* Xk = ws + M4;                  // reused as Opart after proj (2*M4)
    short* Xv = ws + 2 * M4;
    short* Wc0 = ws + 3 * M4;             // reused as lpart after proj
    short* Wc1 = Wc0 + M1;
    short* Wc2 = Wc1 + M1;
    short* Wc3 = Wc2 + M1;
    short* qh = ws + 4 * M4;
    short* kt = ws + 5 * M4;
    short* vh = ws + 6 * M4;
    unsigned long long* maskw = (unsigned long long*)(ws + 7 * M4);
    short* attr = Xq;
    short* Opart = Xk;
    float* lpart = (float*)Wc0;

    CvtArgs cv;
    cv.src[0] = query; cv.dst[0] = Xq;
    cv.src[1] = key;   cv.dst[1] = Xk;
    cv.src[2] = value; cv.dst[2] = Xv;
    cv.src[3] = (const float*)d_in[8];  cv.dst[3] = Wc0;  // Wq
    cv.src[4] = (const float*)d_in[6];  cv.dst[4] = Wc1;  // Wk
    cv.src[5] = (const float*)d_in[4];  cv.dst[5] = Wc2;  // Wv
    cv.src[6] = (const float*)d_in[10]; cv.dst[6] = Wc3;  // Wo
    prep<<<10240, 256, 0, stream>>>(cv, mask, maskw);

    GemmArgs g1;
    g1.X[0] = Xq;  g1.W[0] = Wc0; g1.B[0] = bq; g1.C[0] = qh; g1.scale[0] = QSCALE;
    g1.X[1] = Xv;  g1.W[1] = Wc2; g1.B[1] = bv; g1.C[1] = vh; g1.scale[1] = 1.f;
    g1.X[2] = Wc1; g1.W[2] = Xk;  g1.B[2] = bk; g1.C[2] = kt; g1.scale[2] = 1.f;  // transposed K
    gemm_bt<0, 128><<<dim3(32, 8, 3), 256, 0, stream>>>(g1);

    attn5<<<dim3(16, 32, 2), 256, 0, stream>>>(qh, vh, kt, maskw, Opart, lpart);

    combine<<<2048, 256, 0, stream>>>(Opart, lpart, attr);

    GemmArgs g2;
    g2.X[0] = attr; g2.W[0] = Wc3; g2.B[0] = bo; g2.C[0] = out; g2.scale[0] = 1.f;
    g2.X[1] = attr; g2.W[1] = Wc3; g2.B[1] = bo; g2.C[1] = out; g2.scale[1] = 1.f;
    g2.X[2] = attr; g2.W[2] = Wc3; g2.B[2] = bo; g2.C[2] = out; g2.scale[2] = 1.f;
    gemm_bt<1, 64><<<dim3(64, 8, 1), 256, 0, stream>>>(g2);
}